// Round 3
// baseline (114.023 us; speedup 1.0000x reference)
//
#include <hip/hip_runtime.h>

// VectorQuantizer: N=65536 rows x D=64, K=1024 codes.
// argmin_k ||x - e_k||^2  ==  argmin_k ( ||e_k||^2 - 2 x.e_k )
// Dots via mfma_f32_32x32x16_bf16; gather/outputs/loss in fp32.

#define NROWS 65536
#define DDIM 64
#define KEMB 1024
#define KCHUNK 256
#define NCHUNK (KEMB / KCHUNK)          // 4
#define BLKTHREADS 512                   // 8 waves
#define ROWS_PER_BLOCK 256               // 32 rows per wave
#define NBLOCKS (NROWS / ROWS_PER_BLOCK) // 256 = 1 block/CU
#define LDS_STRIDE 72                    // shorts per emb row (144 B, 16B-aligned)

using bf16x8 = __attribute__((ext_vector_type(8))) short;
using f32x16 = __attribute__((ext_vector_type(16))) float;

__device__ __forceinline__ unsigned short f2bf(float f) {
    union { float f; unsigned u; } v; v.f = f;
    unsigned u = v.u;
    return (unsigned short)((u + 0x7FFFu + ((u >> 16) & 1u)) >> 16);  // RNE
}

__global__ __launch_bounds__(BLKTHREADS) void vq_main(
    const float* __restrict__ lat, const float* __restrict__ emb,
    float* __restrict__ out)
{
    __shared__ short ebf[KCHUNK * LDS_STRIDE];   // 36864 B
    __shared__ float e2f[KCHUNK];                // 1024 B
    __shared__ int   lbk[ROWS_PER_BLOCK];        // 1024 B
    __shared__ float lloss[8];

    const int tid  = threadIdx.x;
    const int lane = tid & 63;
    const int w    = tid >> 6;      // wave 0..7
    const int lo   = lane & 31;
    const int hi   = lane >> 5;
    const int blk  = blockIdx.x;

    const float4* lat4 = (const float4*)lat;
    const float4* emb4 = (const float4*)emb;

    // ---- A fragments: this wave's 32 rows, full D=64, in registers ----
    // 32x32x16 A layout: row = lane&31, kd = (lane>>5)*8 + j; per step s kd += s*16
    const int rowg = blk * ROWS_PER_BLOCK + w * 32 + lo;
    bf16x8 afrag[4];
    #pragma unroll
    for (int s = 0; s < 4; ++s) {
        float4 f0 = lat4[rowg * 16 + s * 4 + hi * 2];
        float4 f1 = lat4[rowg * 16 + s * 4 + hi * 2 + 1];
        bf16x8 a;
        a[0] = (short)f2bf(f0.x); a[1] = (short)f2bf(f0.y);
        a[2] = (short)f2bf(f0.z); a[3] = (short)f2bf(f0.w);
        a[4] = (short)f2bf(f1.x); a[5] = (short)f2bf(f1.y);
        a[6] = (short)f2bf(f1.z); a[7] = (short)f2bf(f1.w);
        afrag[s] = a;
    }

    float best[16];
    int   bk[16];
    #pragma unroll
    for (int j = 0; j < 16; ++j) { best[j] = 3.0e38f; bk[j] = 0; }

    for (int c = 0; c < NCHUNK; ++c) {
        // ---- stage chunk c: KCHUNK codes -> LDS bf16, coalesced ----
        for (int i = tid; i < KCHUNK * 16; i += BLKTHREADS) {
            int r = i >> 4, dg = i & 15;
            float4 v = emb4[(c * KCHUNK + r) * 16 + dg];
            short4 sv;
            sv.x = (short)f2bf(v.x); sv.y = (short)f2bf(v.y);
            sv.z = (short)f2bf(v.z); sv.w = (short)f2bf(v.w);
            *(short4*)&ebf[r * LDS_STRIDE + dg * 4] = sv;
        }
        if (tid < KCHUNK) {   // ||e||^2 in fp32
            float s = 0.f;
            #pragma unroll
            for (int dg = 0; dg < 16; ++dg) {
                float4 v = emb4[(c * KCHUNK + tid) * 16 + dg];
                s += v.x*v.x + v.y*v.y + v.z*v.z + v.w*v.w;
            }
            e2f[tid] = s;
        }
        __syncthreads();

        // ---- 8 k-tiles of 32 codes ----
        for (int kt = 0; kt < KCHUNK / 32; ++kt) {
            const int kl = kt * 32 + lo;
            f32x16 acc;
            #pragma unroll
            for (int j = 0; j < 16; ++j) acc[j] = 0.0f;
            #pragma unroll
            for (int s = 0; s < 4; ++s) {
                bf16x8 b = *(const bf16x8*)&ebf[kl * LDS_STRIDE + s * 16 + hi * 8];
                acc = __builtin_amdgcn_mfma_f32_32x32x16_bf16(afrag[s], b, acc, 0, 0, 0);
            }
            const float e2v  = e2f[kl];
            const int   kglb = c * KCHUNK + kl;
            #pragma unroll
            for (int j = 0; j < 16; ++j) {
                float s = fmaf(-2.0f, acc[j], e2v);   // dist - ||x||^2
                bool u = s < best[j];
                best[j] = u ? s : best[j];
                bk[j]   = u ? kglb : bk[j];
            }
        }
        __syncthreads();
    }

    // ---- cross-lane argmin over the 32 code-columns (within each hi half) ----
    #pragma unroll
    for (int j = 0; j < 16; ++j) {
        float v = best[j]; int k = bk[j];
        #pragma unroll
        for (int m = 16; m >= 1; m >>= 1) {
            float ov = __shfl_xor(v, m);
            int   ok = __shfl_xor(k, m);
            bool t = (ov < v) || (ov == v && ok < k);  // first-index tiebreak
            v = t ? ov : v; k = t ? ok : k;
        }
        best[j] = v; bk[j] = k;
    }
    if (lo == 0) {
        // C/D layout: row = (reg&3) + 8*(reg>>2) + 4*hi
        #pragma unroll
        for (int j = 0; j < 16; ++j) {
            int rloc = (j & 3) + 8 * (j >> 2) + 4 * hi;
            lbk[w * 32 + rloc] = bk[j];
        }
    }
    __syncthreads();

    // ---- output: quantized_st = x + (q - x), loss partial ----
    float loss = 0.f;
    {
        const int row = tid >> 1, half = tid & 1;
        const int rg = blk * ROWS_PER_BLOCK + row;
        const int kb = lbk[row];
        float4* out4 = (float4*)out;
        #pragma unroll
        for (int j = 0; j < 8; ++j) {
            float4 x = lat4[rg * 16 + half * 8 + j];
            float4 q = emb4[kb * 16 + half * 8 + j];
            float dx = q.x - x.x, dy = q.y - x.y, dz = q.z - x.z, dw = q.w - x.w;
            float4 o;
            o.x = x.x + dx; o.y = x.y + dy; o.z = x.z + dz; o.w = x.w + dw;
            loss += dx*dx + dy*dy + dz*dz + dw*dw;
            out4[rg * 16 + half * 8 + j] = o;
        }
    }
    #pragma unroll
    for (int m = 32; m >= 1; m >>= 1) loss += __shfl_down(loss, m);
    if (lane == 0) lloss[w] = loss;
    __syncthreads();
    if (tid == 0) {
        float s = 0.f;
        #pragma unroll
        for (int i = 0; i < 8; ++i) s += lloss[i];
        atomicAdd(&out[NROWS * DDIM], s);   // raw sum; scaled in finalize
    }
}

__global__ void vq_final(float* __restrict__ out) {
    const int L = NROWS * DDIM;
    out[L] = out[L] * (1.25f / (float)(NROWS * DDIM));  // (1+BETA)*mean
}

extern "C" void kernel_launch(void* const* d_in, const int* in_sizes, int n_in,
                              void* d_out, int out_size, void* d_ws, size_t ws_size,
                              hipStream_t stream)
{
    const float* lat = (const float*)d_in[0];
    const float* emb = (const float*)d_in[1];
    float* out = (float*)d_out;
    // zero the loss accumulator slot (d_out is poisoned 0xAA each call)
    hipMemsetAsync(out + (size_t)NROWS * DDIM, 0, sizeof(float), stream);
    vq_main<<<NBLOCKS, BLKTHREADS, 0, stream>>>(lat, emb, out);
    vq_final<<<1, 1, 0, stream>>>(out);
}

// Round 4
// 107.617 us; speedup vs baseline: 1.0595x; 1.0595x over previous
//
#include <hip/hip_runtime.h>

// VectorQuantizer: N=65536 rows x D=64, K=1024 codes.
// argmin_k ||x - e_k||^2  ==  argmin_k ( ||e_k||^2 - 2 x.e_k )
// R3: whole codebook resident in LDS (153 KB), ONE stage+barrier, then
// pure streaming compute. Loss finalize folded in via ticket atomic.

#define NROWS 65536
#define DDIM 64
#define KEMB 1024
#define BLKTHREADS 512                   // 8 waves
#define ROWS_PER_BLOCK 256               // 32 rows per wave
#define NBLOCKS (NROWS / ROWS_PER_BLOCK) // 256 = 1 block/CU
#define LDS_STRIDE 72                    // shorts per emb row (144 B; conflict-free, measured)

using bf16x8 = __attribute__((ext_vector_type(8))) short;
using f32x16 = __attribute__((ext_vector_type(16))) float;

__device__ __forceinline__ unsigned short f2bf(float f) {
    union { float f; unsigned u; } v; v.f = f;
    unsigned u = v.u;
    return (unsigned short)((u + 0x7FFFu + ((u >> 16) & 1u)) >> 16);  // RNE
}

__global__ __launch_bounds__(BLKTHREADS) void vq_main(
    const float* __restrict__ lat, const float* __restrict__ emb,
    float* __restrict__ out, unsigned* __restrict__ ticket,
    float* __restrict__ lossacc)
{
    __shared__ __align__(16) short ebf[KEMB * LDS_STRIDE];  // 147456 B
    __shared__ float e2f[KEMB];                             // 4096 B
    __shared__ int   lbk[ROWS_PER_BLOCK];                   // 1024 B
    __shared__ float lloss[8];

    const int tid  = threadIdx.x;
    const int lane = tid & 63;
    const int w    = tid >> 6;      // wave 0..7
    const int lo   = lane & 31;
    const int hi   = lane >> 5;
    const int blk  = blockIdx.x;

    const float4* lat4 = (const float4*)lat;
    const float4* emb4 = (const float4*)emb;

    // ---- A fragments: this wave's 32 rows, full D=64, in registers ----
    // 32x32x16 A layout: row = lane&31, kd = (lane>>5)*8 + j; step s adds s*16
    const int rowg = blk * ROWS_PER_BLOCK + w * 32 + lo;
    bf16x8 afrag[4];
    #pragma unroll
    for (int s = 0; s < 4; ++s) {
        float4 f0 = lat4[rowg * 16 + s * 4 + hi * 2];
        float4 f1 = lat4[rowg * 16 + s * 4 + hi * 2 + 1];
        bf16x8 a;
        a[0] = (short)f2bf(f0.x); a[1] = (short)f2bf(f0.y);
        a[2] = (short)f2bf(f0.z); a[3] = (short)f2bf(f0.w);
        a[4] = (short)f2bf(f1.x); a[5] = (short)f2bf(f1.y);
        a[6] = (short)f2bf(f1.z); a[7] = (short)f2bf(f1.w);
        afrag[s] = a;
    }

    // ---- stage ENTIRE codebook -> LDS bf16 (+ ||e||^2), once ----
    for (int r = tid; r < KEMB; r += BLKTHREADS) {   // 2 rows/thread
        float e2 = 0.f;
        #pragma unroll
        for (int g = 0; g < 8; ++g) {
            float4 v0 = emb4[r * 16 + g * 2];
            float4 v1 = emb4[r * 16 + g * 2 + 1];
            e2 += v0.x*v0.x + v0.y*v0.y + v0.z*v0.z + v0.w*v0.w
                + v1.x*v1.x + v1.y*v1.y + v1.z*v1.z + v1.w*v1.w;
            bf16x8 b;
            b[0] = (short)f2bf(v0.x); b[1] = (short)f2bf(v0.y);
            b[2] = (short)f2bf(v0.z); b[3] = (short)f2bf(v0.w);
            b[4] = (short)f2bf(v1.x); b[5] = (short)f2bf(v1.y);
            b[6] = (short)f2bf(v1.z); b[7] = (short)f2bf(v1.w);
            *(bf16x8*)&ebf[r * LDS_STRIDE + g * 8] = b;
        }
        e2f[r] = e2;
    }
    __syncthreads();

    // ---- 32 k-tiles of 32 codes, no further barriers ----
    float best[16];
    int   bk[16];
    #pragma unroll
    for (int j = 0; j < 16; ++j) { best[j] = 3.0e38f; bk[j] = 0; }

    #pragma unroll 4
    for (int kt = 0; kt < KEMB / 32; ++kt) {
        const int kl = kt * 32 + lo;
        f32x16 acc;
        #pragma unroll
        for (int j = 0; j < 16; ++j) acc[j] = 0.0f;
        #pragma unroll
        for (int s = 0; s < 4; ++s) {
            bf16x8 b = *(const bf16x8*)&ebf[kl * LDS_STRIDE + s * 16 + hi * 8];
            acc = __builtin_amdgcn_mfma_f32_32x32x16_bf16(afrag[s], b, acc, 0, 0, 0);
        }
        const float e2v = e2f[kl];
        #pragma unroll
        for (int j = 0; j < 16; ++j) {
            float s = fmaf(-2.0f, acc[j], e2v);   // dist - ||x||^2
            bool u = s < best[j];
            best[j] = u ? s : best[j];
            bk[j]   = u ? kl : bk[j];
        }
    }

    // ---- cross-lane argmin over the 32 code-columns ----
    #pragma unroll
    for (int j = 0; j < 16; ++j) {
        float v = best[j]; int k = bk[j];
        #pragma unroll
        for (int m = 16; m >= 1; m >>= 1) {
            float ov = __shfl_xor(v, m);
            int   ok = __shfl_xor(k, m);
            bool t = (ov < v) || (ov == v && ok < k);  // first-index tiebreak
            v = t ? ov : v; k = t ? ok : k;
        }
        best[j] = v; bk[j] = k;
    }
    if (lo == 0) {
        // C/D layout: row = (reg&3) + 8*(reg>>2) + 4*hi
        #pragma unroll
        for (int j = 0; j < 16; ++j) {
            int rloc = (j & 3) + 8 * (j >> 2) + 4 * hi;
            lbk[w * 32 + rloc] = bk[j];
        }
    }
    __syncthreads();

    // ---- output: quantized_st = x + (q - x), loss partial ----
    float loss = 0.f;
    {
        const int row = tid >> 1, half = tid & 1;
        const int rg = blk * ROWS_PER_BLOCK + row;
        const int kb = lbk[row];
        float4* out4 = (float4*)out;
        #pragma unroll
        for (int j = 0; j < 8; ++j) {
            float4 x = lat4[rg * 16 + half * 8 + j];
            float4 q = emb4[kb * 16 + half * 8 + j];
            float dx = q.x - x.x, dy = q.y - x.y, dz = q.z - x.z, dw = q.w - x.w;
            float4 o;
            o.x = x.x + dx; o.y = x.y + dy; o.z = x.z + dz; o.w = x.w + dw;
            loss += dx*dx + dy*dy + dz*dz + dw*dw;
            out4[rg * 16 + half * 8 + j] = o;
        }
    }
    #pragma unroll
    for (int m = 32; m >= 1; m >>= 1) loss += __shfl_down(loss, m);
    if (lane == 0) lloss[w] = loss;
    __syncthreads();

    if (tid == 0) {
        float part = 0.f;
        #pragma unroll
        for (int i = 0; i < 8; ++i) part += lloss[i];
        // device-coherent accumulate; returned value forces completion
        float old = atomicAdd(lossacc, part);
        asm volatile("" :: "v"(old) : "memory");
        unsigned t = atomicAdd(ticket, 1u);
        if (t == NBLOCKS - 1) {               // last block: all adds visible
            float tot = atomicAdd(lossacc, 0.0f);   // coherent read
            out[NROWS * DDIM] = tot * (1.25f / (float)(NROWS * DDIM));
        }
    }
}

extern "C" void kernel_launch(void* const* d_in, const int* in_sizes, int n_in,
                              void* d_out, int out_size, void* d_ws, size_t ws_size,
                              hipStream_t stream)
{
    const float* lat = (const float*)d_in[0];
    const float* emb = (const float*)d_in[1];
    float* out = (float*)d_out;
    unsigned* ticket = (unsigned*)d_ws;          // ws[0]
    float* lossacc = (float*)d_ws + 1;           // ws[1]
    hipMemsetAsync(d_ws, 0, 8, stream);          // zero ticket + loss accum
    vq_main<<<NBLOCKS, BLKTHREADS, 0, stream>>>(lat, emb, out, ticket, lossacc);
}